// Round 1
// baseline (268.427 us; speedup 1.0000x reference)
//
#include <hip/hip_runtime.h>
#include <hip/hip_fp16.h>

#define NNEI   138
#define SEL0   46
#define NDESC  552
#define GROW   100   // padded half-row stride for g_lds (2-way banks = free)

__device__ __forceinline__ float fast_tanh(float x) {
    float z = __expf(2.0f * x);                  // v_mul + v_exp
    float r = __builtin_amdgcn_rcpf(z + 1.0f);   // v_add + v_rcp
    return __builtin_fmaf(-2.0f, r, 1.0f);       // 1 - 2/(e^{2x}+1); x->+inf => 1, x->-inf => -1
}

__global__ __launch_bounds__(192, 3)
void emb_net_kernel(const float* __restrict__ dmat,
                    const float* __restrict__ w00, const float* __restrict__ b00,
                    const float* __restrict__ w01, const float* __restrict__ b01,
                    const float* __restrict__ w02, const float* __restrict__ b02,
                    const float* __restrict__ w10, const float* __restrict__ b10,
                    const float* __restrict__ w11, const float* __restrict__ b11,
                    const float* __restrict__ w12, const float* __restrict__ b12,
                    float* __restrict__ out)
{
    __shared__ __half g_lds[NNEI * GROW];          // [s][e] fp16, padded
    __shared__ alignas(16) float dd_lds[NNEI * 4]; // [s][4]
    __shared__ float part_lds[2 * 4 * 96];         // [half][d][e]
    __shared__ float xs_lds[4 * 96];               // [d][e]
    __shared__ float res_lds[768];                 // [e][k]

    const int tid = threadIdx.x;
    const int n   = blockIdx.x;

    // wave-type-pure neighbor mapping:
    // wave0: s = tid (active tid<46, type0); waves1-2: s = tid-18 (active tid<156, type1)
    int ty = __builtin_amdgcn_readfirstlane(tid >= 64 ? 1 : 0);
    const int  s   = (tid < 64) ? tid : (tid - 18);
    const bool act = (tid < 64) ? (tid < SEL0) : (tid < 156);

    const float* __restrict__ W0 = ty ? w10 : w00;
    const float* __restrict__ B0 = ty ? b10 : b00;
    const float* __restrict__ W1 = ty ? w11 : w01;
    const float* __restrict__ B1 = ty ? b11 : b01;
    const float* __restrict__ W2 = ty ? w12 : w02;
    const float* __restrict__ B2 = ty ? b12 : b02;

    // ---------------- phase 1: per-neighbor MLP ----------------
    if (act) {
        const float4 dd = *reinterpret_cast<const float4*>(dmat + (size_t)n * NDESC + s * 4);
        *reinterpret_cast<float4*>(&dd_lds[s * 4]) = dd;
        const float x = dd.x;

        float h0[24];
#pragma unroll
        for (int j = 0; j < 24; ++j)
            h0[j] = fast_tanh(__builtin_fmaf(x, W0[j], B0[j]));

        float h1[48];
#pragma unroll
        for (int k = 0; k < 48; ++k) h1[k] = B1[k];
#pragma unroll
        for (int j = 0; j < 24; ++j) {
            const float hj = h0[j];
#pragma unroll
            for (int k = 0; k < 48; ++k)
                h1[k] = __builtin_fmaf(hj, W1[j * 48 + k], h1[k]);
        }
#pragma unroll
        for (int k = 0; k < 48; ++k)
            h1[k] = fast_tanh(h1[k]) + h0[(k < 24) ? k : (k - 24)];

        // layer 2 in two e-halves of 48 (keeps VGPR < 128)
#pragma unroll
        for (int hfe = 0; hfe < 2; ++hfe) {
            float g[48];
#pragma unroll
            for (int e = 0; e < 48; ++e) g[e] = B2[hfe * 48 + e];
#pragma unroll
            for (int k = 0; k < 48; ++k) {
                const float hk = h1[k];
#pragma unroll
                for (int e = 0; e < 48; ++e)
                    g[e] = __builtin_fmaf(hk, W2[k * 96 + hfe * 48 + e], g[e]);
            }
#pragma unroll
            for (int e = 0; e < 48; ++e) {
                const float ge = fast_tanh(g[e]) + h1[e];   // residual h1[(hfe*48+e)%48] == h1[e]
                g_lds[s * GROW + hfe * 48 + e] = __float2half(ge);
            }
        }
    }
    __syncthreads();

    // ---------------- phase 2: acc[d][e] = sum_s dd[s][d]*g[s][e] ----------------
    {
        const int e  = tid % 96;
        const int hf = tid / 96;
        const int s0 = hf * 69;
        float a0 = 0.f, a1 = 0.f, a2 = 0.f, a3 = 0.f;
#pragma unroll 4
        for (int i = 0; i < 69; ++i) {
            const int ss = s0 + i;
            const float gv  = __half2float(g_lds[ss * GROW + e]);
            const float4 dv = *reinterpret_cast<const float4*>(&dd_lds[ss * 4]); // LDS broadcast
            a0 = __builtin_fmaf(dv.x, gv, a0);
            a1 = __builtin_fmaf(dv.y, gv, a1);
            a2 = __builtin_fmaf(dv.z, gv, a2);
            a3 = __builtin_fmaf(dv.w, gv, a3);
        }
        part_lds[hf * 384 +   0 + e] = a0;
        part_lds[hf * 384 +  96 + e] = a1;
        part_lds[hf * 384 + 192 + e] = a2;
        part_lds[hf * 384 + 288 + e] = a3;
    }
    __syncthreads();

    // ---------------- phase 3: xs = acc/138; res[e][k] = sum_d xs[d][e]*xs[d][k] ----------------
    float xs0 = 0.f, xs1 = 0.f, xs2 = 0.f, xs3 = 0.f;
    if (tid < 96) {
        constexpr float inv = 1.0f / 138.0f;
        xs0 = (part_lds[        tid] + part_lds[384 +       tid]) * inv;
        xs1 = (part_lds[ 96 +  tid] + part_lds[384 +  96 + tid]) * inv;
        xs2 = (part_lds[192 +  tid] + part_lds[384 + 192 + tid]) * inv;
        xs3 = (part_lds[288 +  tid] + part_lds[384 + 288 + tid]) * inv;
        xs_lds[        tid] = xs0;
        xs_lds[ 96 +  tid] = xs1;
        xs_lds[192 +  tid] = xs2;
        xs_lds[288 +  tid] = xs3;
    }
    __syncthreads();
    if (tid < 96) {
#pragma unroll
        for (int k = 0; k < 8; ++k) {
            float r = xs0 * xs_lds[k];
            r = __builtin_fmaf(xs1, xs_lds[ 96 + k], r);
            r = __builtin_fmaf(xs2, xs_lds[192 + k], r);
            r = __builtin_fmaf(xs3, xs_lds[288 + k], r);
            res_lds[tid * 8 + k] = r;
        }
    }
    __syncthreads();

    // coalesced output copy: out[n*768 + e*8 + k]
#pragma unroll
    for (int i = 0; i < 4; ++i)
        out[(size_t)n * 768 + i * 192 + tid] = res_lds[i * 192 + tid];
}

extern "C" void kernel_launch(void* const* d_in, const int* in_sizes, int n_in,
                              void* d_out, int out_size, void* d_ws, size_t ws_size,
                              hipStream_t stream)
{
    const float* dmat = (const float*)d_in[0];
    const int n_atoms = in_sizes[0] / NDESC;   // 6144
    emb_net_kernel<<<n_atoms, 192, 0, stream>>>(
        dmat,
        (const float*)d_in[1],  (const float*)d_in[2],
        (const float*)d_in[3],  (const float*)d_in[4],
        (const float*)d_in[5],  (const float*)d_in[6],
        (const float*)d_in[7],  (const float*)d_in[8],
        (const float*)d_in[9],  (const float*)d_in[10],
        (const float*)d_in[11], (const float*)d_in[12],
        (float*)d_out);
}

// Round 2
// 184.363 us; speedup vs baseline: 1.4560x; 1.4560x over previous
//
#include <hip/hip_runtime.h>
#include <hip/hip_fp16.h>

typedef _Float16 f16;
typedef _Float16 f16x8 __attribute__((ext_vector_type(8)));
typedef _Float16 f16x4 __attribute__((ext_vector_type(4)));
typedef float    f32x4 __attribute__((ext_vector_type(4)));

#define GSTRIDE 152   // padded row length (halves) for G[e][r]; 304B = 16B-aligned, odd/32 word stride

__device__ __forceinline__ float fast_tanh(float x) {
    float z = __expf(2.0f * x);                  // v_mul + v_exp
    float r = __builtin_amdgcn_rcpf(z + 1.0f);   // v_add + v_rcp
    return __builtin_fmaf(-2.0f, r, 1.0f);       // 1 - 2/(e^{2x}+1)
}

// rows r: 0..45 = type0 (s=r), pads 46,47; 48..139 = type1 (s=r-2), pads 140..143.
// 9 row-tiles of 16: tiles 0-2 type0, 3-8 type1.
__global__ __launch_bounds__(256, 2)
void emb_net_kernel(const float* __restrict__ dmat,
                    const float* __restrict__ w00, const float* __restrict__ b00,
                    const float* __restrict__ w01, const float* __restrict__ b01,
                    const float* __restrict__ w02, const float* __restrict__ b02,
                    const float* __restrict__ w10, const float* __restrict__ b10,
                    const float* __restrict__ w11, const float* __restrict__ b11,
                    const float* __restrict__ w12, const float* __restrict__ b12,
                    float* __restrict__ out)
{
    __shared__ alignas(16) f16  W2T[2 * 96 * 48];     // [ty][e][k] fp16 (B^T: contiguous k)
    __shared__ alignas(16) f16  H1[9 * 6 * 16 * 8];   // [tile][chunk][lane16][8] A-frag order
    __shared__ alignas(16) f16  G[96 * GSTRIDE];      // [e][r] fp16, column-major for phase 2
    __shared__ alignas(16) float DD[144 * 4];         // [r][4], pad rows zero
    __shared__ float B2s[2 * 96];
    __shared__ float PART[2 * 4 * 96];
    __shared__ float XSH[4 * 96];
    __shared__ float RESH[768];

    const int tid  = threadIdx.x;
    const int n    = blockIdx.x;
    const int wave = tid >> 6;
    const int lane = tid & 63;

    // ---------------- stage 0: dd, W2^T (fp16), b2, zero pads ----------------
    if (tid < 144) {
        const int  r     = tid;
        const bool isT0  = r < 48;
        const int  s     = isT0 ? r : (r - 2);          // type1: s = 46 + (r-48)
        const bool valid = isT0 ? (r < 46) : (r < 140);
        float4 v = make_float4(0.f, 0.f, 0.f, 0.f);
        if (valid) v = *reinterpret_cast<const float4*>(dmat + (size_t)n * 552 + s * 4);
        *reinterpret_cast<float4*>(&DD[r * 4]) = v;
    }
#pragma unroll 4
    for (int i = 0; i < 36; ++i) {                      // 2*48*96 = 9216 weights
        const int idx = tid + i * 256;
        const int ty  = idx >= 4608;                    // wave-uniform per i
        const int rem = idx - ty * 4608;
        const int k   = rem / 96;
        const int e   = rem - k * 96;
        const float v = (ty ? w12 : w02)[rem];
        W2T[(ty * 96 + e) * 48 + k] = (f16)v;
    }
    if (tid < 192) B2s[tid] = (tid < 96) ? b02[tid] : b12[tid - 96];
    if (tid < 36) {                                     // zero H1 pad rows (NaN safety for MFMA)
        const int rr = tid / 6, c = tid - rr * 6;
        const int t  = (rr < 2) ? 2 : 8;
        const int rl = (rr < 2) ? (14 + rr) : (10 + rr);
        f16x8 z = {};
        *reinterpret_cast<f16x8*>(&H1[((t * 6 + c) * 16 + rl) * 8]) = z;
    }
    __syncthreads();

    // ---------------- stage 1: layers 0/1 on VALU, wave-type-pure ----------------
    {
        int r = -1, tyv = 0;
        if (wave == 0)      { if (lane < 46) r = lane;       tyv = 0; }
        else if (wave == 1) { r = 48 + lane;                 tyv = 1; }
        else if (wave == 2) { if (lane < 28) r = 112 + lane; tyv = 1; }
        if (r >= 0) {
            const int ty = __builtin_amdgcn_readfirstlane(tyv);
            const float* __restrict__ W0 = ty ? w10 : w00;
            const float* __restrict__ B0 = ty ? b10 : b00;
            const float* __restrict__ W1 = ty ? w11 : w01;
            const float* __restrict__ B1 = ty ? b11 : b01;
            const float x = DD[r * 4];

            float h0[24];
#pragma unroll
            for (int j = 0; j < 24; ++j)
                h0[j] = fast_tanh(__builtin_fmaf(x, W0[j], B0[j]));

            float h1v[48];
#pragma unroll
            for (int k = 0; k < 48; ++k) h1v[k] = B1[k];
#pragma unroll
            for (int j = 0; j < 24; ++j) {
                const float hj = h0[j];
#pragma unroll
                for (int k = 0; k < 48; ++k)
                    h1v[k] = __builtin_fmaf(hj, W1[j * 48 + k], h1v[k]);
            }
#pragma unroll
            for (int k = 0; k < 48; ++k)
                h1v[k] = fast_tanh(h1v[k]) + h0[(k < 24) ? k : (k - 24)];

            // store fp16 in A-fragment order: [tile][chunk c=k/8][row&15][k&7]
            const int t = r >> 4, rl = r & 15;
#pragma unroll
            for (int c = 0; c < 6; ++c) {
                f16x8 pk;
#pragma unroll
                for (int j = 0; j < 8; ++j) pk[j] = (f16)h1v[c * 8 + j];
                *reinterpret_cast<f16x8*>(&H1[((t * 6 + c) * 16 + rl) * 8]) = pk;
            }
        }
    }
    __syncthreads();

    // ---------------- stage 2: layer 2 via MFMA 16x16x32 f16 (K=48 = 32+16pad) ----------------
    {
        const int l15 = lane & 15, lhi = lane >> 4;
        const int ustart = (wave * 54) >> 2;            // 54 units (t,ct) over 4 waves
        const int uend   = ((wave + 1) * 54) >> 2;
        for (int u = ustart; u < uend; ++u) {
            const int t   = u / 6;
            const int ct  = u - t * 6;
            const int tyt = (t >= 3);
            const int e   = ct * 16 + l15;

            f16x8 a0 = *reinterpret_cast<const f16x8*>(&H1[((t * 6 + lhi) * 16 + l15) * 8]);
            const f16* Bb = &W2T[(tyt * 96 + e) * 48];
            f16x8 b0 = *reinterpret_cast<const f16x8*>(&Bb[lhi * 8]);
            f16x8 a1 = {}, b1 = {};
            if (lhi < 2) {                               // k 32..47 real, k 48..63 zero-pad
                a1 = *reinterpret_cast<const f16x8*>(&H1[((t * 6 + 4 + lhi) * 16 + l15) * 8]);
                b1 = *reinterpret_cast<const f16x8*>(&Bb[32 + lhi * 8]);
            }
            f32x4 acc = {0.f, 0.f, 0.f, 0.f};
            acc = __builtin_amdgcn_mfma_f32_16x16x32_f16(a0, b0, acc, 0, 0, 0);
            acc = __builtin_amdgcn_mfma_f32_16x16x32_f16(a1, b1, acc, 0, 0, 0);

            const float bias = B2s[tyt * 96 + e];
            const int k48 = (e < 48) ? e : (e - 48);     // residual index
            const int cch = k48 >> 3, cj = k48 & 7;
            f16x4 gpk;
#pragma unroll
            for (int rg = 0; rg < 4; ++rg) {             // C: row=(lane>>4)*4+rg, col=lane&15
                const int rl2 = lhi * 4 + rg;
                const float h1r = (float)H1[((t * 6 + cch) * 16 + rl2) * 8 + cj];
                gpk[rg] = (f16)(fast_tanh(acc[rg] + bias) + h1r);
            }
            *reinterpret_cast<f16x4*>(&G[e * GSTRIDE + t * 16 + lhi * 4]) = gpk;
        }
    }
    __syncthreads();

    // ---------------- stage 3: acc[d][e] = sum_r dd[r][d]*g[r][e] (pads: dd=0) ----------------
    if (tid < 192) {
        const int e  = tid % 96;
        const int hf = tid / 96;
        const int r0 = hf * 72;
        float a0 = 0.f, a1 = 0.f, a2 = 0.f, a3 = 0.f;
#pragma unroll
        for (int i8 = 0; i8 < 9; ++i8) {
            const f16x8 g8 = *reinterpret_cast<const f16x8*>(&G[e * GSTRIDE + r0 + i8 * 8]);
#pragma unroll
            for (int j = 0; j < 8; ++j) {
                const float gv = (float)g8[j];
                const float4 dv = *reinterpret_cast<const float4*>(&DD[(r0 + i8 * 8 + j) * 4]);
                a0 = __builtin_fmaf(dv.x, gv, a0);
                a1 = __builtin_fmaf(dv.y, gv, a1);
                a2 = __builtin_fmaf(dv.z, gv, a2);
                a3 = __builtin_fmaf(dv.w, gv, a3);
            }
        }
        PART[hf * 384 +   0 + e] = a0;
        PART[hf * 384 +  96 + e] = a1;
        PART[hf * 384 + 192 + e] = a2;
        PART[hf * 384 + 288 + e] = a3;
    }
    __syncthreads();

    // ---------------- stage 4: xs = acc/138; res[e][k] = sum_d xs[d][e]*xs[d][k] ----------------
    float xs0 = 0.f, xs1 = 0.f, xs2 = 0.f, xs3 = 0.f;
    if (tid < 96) {
        constexpr float inv = 1.0f / 138.0f;
        xs0 = (PART[        tid] + PART[384 +       tid]) * inv;
        xs1 = (PART[ 96 +  tid] + PART[384 +  96 + tid]) * inv;
        xs2 = (PART[192 +  tid] + PART[384 + 192 + tid]) * inv;
        xs3 = (PART[288 +  tid] + PART[384 + 288 + tid]) * inv;
        XSH[        tid] = xs0;
        XSH[ 96 +  tid] = xs1;
        XSH[192 +  tid] = xs2;
        XSH[288 +  tid] = xs3;
    }
    __syncthreads();
    if (tid < 96) {
#pragma unroll
        for (int k = 0; k < 8; ++k) {
            float rr = xs0 * XSH[k];
            rr = __builtin_fmaf(xs1, XSH[ 96 + k], rr);
            rr = __builtin_fmaf(xs2, XSH[192 + k], rr);
            rr = __builtin_fmaf(xs3, XSH[288 + k], rr);
            RESH[tid * 8 + k] = rr;
        }
    }
    __syncthreads();

#pragma unroll
    for (int i = 0; i < 3; ++i)
        out[(size_t)n * 768 + i * 256 + tid] = RESH[i * 256 + tid];
}

extern "C" void kernel_launch(void* const* d_in, const int* in_sizes, int n_in,
                              void* d_out, int out_size, void* d_ws, size_t ws_size,
                              hipStream_t stream)
{
    const float* dmat = (const float*)d_in[0];
    const int n_atoms = in_sizes[0] / 552;   // 6144
    emb_net_kernel<<<n_atoms, 256, 0, stream>>>(
        dmat,
        (const float*)d_in[1],  (const float*)d_in[2],
        (const float*)d_in[3],  (const float*)d_in[4],
        (const float*)d_in[5],  (const float*)d_in[6],
        (const float*)d_in[7],  (const float*)d_in[8],
        (const float*)d_in[9],  (const float*)d_in[10],
        (const float*)d_in[11], (const float*)d_in[12],
        (float*)d_out);
}

// Round 3
// 122.246 us; speedup vs baseline: 2.1958x; 1.5081x over previous
//
#include <hip/hip_runtime.h>
#include <hip/hip_fp16.h>

typedef _Float16 f16;
typedef _Float16 f16x8 __attribute__((ext_vector_type(8)));
typedef _Float16 f16x4 __attribute__((ext_vector_type(4)));
typedef float    f32x4 __attribute__((ext_vector_type(4)));

#define W1P 40                 // W1T col pitch (halves): 80B = 20 words -> odd bank-group stride
#define W2P 56                 // W2T col pitch (halves): 112B = 28 words -> 7 groups, coprime w/ 8
#define W1E (2*48*W1P)         // 3840
#define W2E (2*96*W2P)         // 10752
#define GS  152                // G / DDT row pitch (halves): 304B = 19 groups, coprime w/ 8
#define HP  144                // H0/H1 chunk pitch (halves): 288B = 18 groups -> phase-wise 2-way

__device__ __forceinline__ float fast_tanh(float x) {
    float z = __expf(2.0f * x);                  // v_mul, v_mul, v_exp
    float r = __builtin_amdgcn_rcpf(z + 1.0f);   // v_add, v_rcp
    return __builtin_fmaf(-2.0f, r, 1.0f);       // 1 - 2/(e^{2x}+1)
}

// one-time weight conversion into d_ws: W1T[ty][n][k] (k<24 real, rest 0),
// W2T[ty][e][k] (k<48 real, rest 0) — fp16 B-fragment-friendly layouts.
__global__ __launch_bounds__(256)
void setup_weights(const float* __restrict__ w01, const float* __restrict__ w11,
                   const float* __restrict__ w02, const float* __restrict__ w12,
                   f16* __restrict__ ws)
{
    const int tid0   = blockIdx.x * 256 + threadIdx.x;
    const int stride = gridDim.x * 256;
    for (int idx = tid0; idx < W1E; idx += stride) {
        const int ty  = idx / (48 * W1P);
        const int rem = idx - ty * 48 * W1P;
        const int nn  = rem / W1P, k = rem - nn * W1P;
        const float v = (k < 24) ? (ty ? w11 : w01)[k * 48 + nn] : 0.f;
        ws[idx] = (f16)v;
    }
    f16* W2T = ws + W1E;
    for (int idx = tid0; idx < W2E; idx += stride) {
        const int ty  = idx / (96 * W2P);
        const int rem = idx - ty * 96 * W2P;
        const int e   = rem / W2P, k = rem - e * W2P;
        const float v = (k < 48) ? (ty ? w12 : w02)[k * 96 + e] : 0.f;
        W2T[idx] = (f16)v;
    }
}

// rows r: 0..45 type0 (s=r), 46/47 pad; 48..139 type1 (s=r-2), 140..143 pad.
__global__ __launch_bounds__(256, 2)
void emb_main(const float* __restrict__ dmat,
              const float* __restrict__ w00, const float* __restrict__ b00,
              const float* __restrict__ b01, const float* __restrict__ b02,
              const float* __restrict__ w10, const float* __restrict__ b10,
              const float* __restrict__ b11, const float* __restrict__ b12,
              const f16* __restrict__ ws,
              float* __restrict__ out)
{
    __shared__ f16   H0[9 * 3 * HP];    // [t][c][r*8+j] A-frag order, K=24
    __shared__ f16   H1[9 * 6 * HP];    // [t][c][r*8+j] A-frag order, K=48
    __shared__ f16   G[96 * GS];        // [e][r]
    __shared__ f16   DDT[16 * GS];      // [d(16, 4 live)][r], pads zero
    __shared__ float B1s[96];
    __shared__ float B2s[192];
    __shared__ float XSH[4 * 96];
    __shared__ float RESH[768];

    const int tid  = threadIdx.x, n = blockIdx.x;
    const int wave = tid >> 6,  lane = tid & 63;
    const int l15  = lane & 15, lhi  = lane >> 4;
    const f16* __restrict__ W1T = ws;
    const f16* __restrict__ W2T = ws + W1E;

    // ---------------- stage 0: DDT (f16, zero-padded), H0 pad rows, biases ----------------
    if (tid < GS) {
        const int r = tid;
        float4 v = make_float4(0.f, 0.f, 0.f, 0.f);
        if (r < 144) {
            const bool t0 = r < 48;
            const int  s  = t0 ? r : (r - 2);
            const bool ok = t0 ? (r < 46) : (r < 140);
            if (ok) v = *reinterpret_cast<const float4*>(dmat + (size_t)n * 552 + s * 4);
        }
        DDT[0 * GS + r] = (f16)v.x;
        DDT[1 * GS + r] = (f16)v.y;
        DDT[2 * GS + r] = (f16)v.z;
        DDT[3 * GS + r] = (f16)v.w;
#pragma unroll
        for (int d = 4; d < 16; ++d) DDT[d * GS + r] = (f16)0.f;
    }
    if (tid < 18) {                       // zero H0 pad rows {46,47,140..143}
        const int q = tid / 3, c = tid - q * 3;
        const int r = (q < 2) ? (46 + q) : (138 + q);
        const int t = r >> 4, rl = r & 15;
        f16x8 z = {};
        *reinterpret_cast<f16x8*>(&H0[(t * 3 + c) * HP + rl * 8]) = z;
    }
    if (tid < 96)  B1s[tid] = (tid < 48) ? b01[tid] : b11[tid - 48];
    if (tid < 192) B2s[tid] = (tid < 96) ? b02[tid] : b12[tid - 96];
    __syncthreads();

    // ---------------- stage 1: L0 on VALU, wave-type-pure ----------------
    {
        int r = -1, tyv = 0;
        if (wave == 0)      { if (lane < 46) r = lane; }
        else if (wave == 1) { r = 48 + lane; tyv = 1; }
        else if (wave == 2) { if (lane < 28) r = 112 + lane; tyv = 1; }
        if (r >= 0) {
            const int ty = __builtin_amdgcn_readfirstlane(tyv);
            const float* __restrict__ W0 = ty ? w10 : w00;
            const float* __restrict__ B0 = ty ? b10 : b00;
            const int s = (r < 48) ? r : (r - 2);
            const float x = dmat[(size_t)n * 552 + s * 4];
            float h0[24];
#pragma unroll
            for (int j = 0; j < 24; ++j)
                h0[j] = fast_tanh(__builtin_fmaf(x, W0[j], B0[j]));
            const int t = r >> 4, rl = r & 15;
#pragma unroll
            for (int c = 0; c < 3; ++c) {
                f16x8 pk;
#pragma unroll
                for (int j = 0; j < 8; ++j) pk[j] = (f16)h0[c * 8 + j];
                *reinterpret_cast<f16x8*>(&H0[(t * 3 + c) * HP + rl * 8]) = pk;
            }
        }
    }
    __syncthreads();

    // ---------------- stage 2a: L1 MFMA (K=24 pad 32), 27 units ----------------
#pragma unroll
    for (int i = 0; i < 7; ++i) {
        const int u = wave + 4 * i;
        if (u < 27) {
            const int t = u / 3, ct = u - t * 3;
            const int tyt = (t >= 3);
            const int e1  = ct * 16 + l15;           // 0..47
            f16x8 a = {};
            if (lhi < 3) a = *reinterpret_cast<const f16x8*>(&H0[(t * 3 + lhi) * HP + l15 * 8]);
            const f16x8 b = *reinterpret_cast<const f16x8*>(&W1T[(tyt * 48 + e1) * W1P + lhi * 8]);
            f32x4 acc = {};
            acc = __builtin_amdgcn_mfma_f32_16x16x32_f16(a, b, acc, 0, 0, 0);
            const float bias = B1s[tyt * 48 + e1];
            const int rm = (e1 < 24) ? e1 : (e1 - 24);
            const int cch = rm >> 3, cj = rm & 7;
#pragma unroll
            for (int rg = 0; rg < 4; ++rg) {         // C: col=lane&15, row=(lane>>4)*4+rg
                const int row = lhi * 4 + rg;
                const float h0r = (float)H0[(t * 3 + cch) * HP + row * 8 + cj];
                H1[(t * 6 + (e1 >> 3)) * HP + row * 8 + (e1 & 7)] =
                    (f16)(fast_tanh(acc[rg] + bias) + h0r);
            }
        }
    }
    __syncthreads();

    // ---------------- stage 2b: L2 MFMA (K=48 = 32+16pad), 54 units ----------------
#pragma unroll
    for (int i = 0; i < 14; ++i) {
        const int u = wave + 4 * i;
        if (u < 54) {
            const int t = u / 6, ct = u - t * 6;
            const int tyt = (t >= 3);
            const int e = ct * 16 + l15;             // 0..95
            const f16* Bp = &W2T[(tyt * 96 + e) * W2P];
            f16x8 a0 = *reinterpret_cast<const f16x8*>(&H1[(t * 6 + lhi) * HP + l15 * 8]);
            f16x8 b0 = *reinterpret_cast<const f16x8*>(&Bp[lhi * 8]);
            f16x8 a1 = {}, b1 = {};
            if (lhi < 2) {
                a1 = *reinterpret_cast<const f16x8*>(&H1[(t * 6 + 4 + lhi) * HP + l15 * 8]);
                b1 = *reinterpret_cast<const f16x8*>(&Bp[32 + lhi * 8]);
            }
            f32x4 acc = {};
            acc = __builtin_amdgcn_mfma_f32_16x16x32_f16(a0, b0, acc, 0, 0, 0);
            acc = __builtin_amdgcn_mfma_f32_16x16x32_f16(a1, b1, acc, 0, 0, 0);
            const float bias = B2s[tyt * 96 + e];
            const int k48 = (e < 48) ? e : (e - 48);
            const int cch = k48 >> 3, cj = k48 & 7;
            f16x4 gp;
#pragma unroll
            for (int rg = 0; rg < 4; ++rg) {
                const int row = lhi * 4 + rg;
                const float h1r = (float)H1[(t * 6 + cch) * HP + row * 8 + cj];
                gp[rg] = (f16)(fast_tanh(acc[rg] + bias) + h1r);
            }
            *reinterpret_cast<f16x4*>(&G[e * GS + t * 16 + lhi * 4]) = gp;
        }
    }
    __syncthreads();

    // ---------------- stage 3: acc[d][e] = dd^T @ G via MFMA (K=144 = 4*32+16) ----------------
#pragma unroll
    for (int i = 0; i < 2; ++i) {
        const int ct = wave + 4 * i;
        if (ct < 6) {
            const int e = ct * 16 + l15;
            f32x4 acc = {};
#pragma unroll
            for (int st = 0; st < 4; ++st) {
                f16x8 a = *reinterpret_cast<const f16x8*>(&DDT[l15 * GS + st * 32 + lhi * 8]);
                f16x8 b = *reinterpret_cast<const f16x8*>(&G[e * GS + st * 32 + lhi * 8]);
                acc = __builtin_amdgcn_mfma_f32_16x16x32_f16(a, b, acc, 0, 0, 0);
            }
            f16x8 a = {}, b = {};
            if (lhi < 2) {
                a = *reinterpret_cast<const f16x8*>(&DDT[l15 * GS + 128 + lhi * 8]);
                b = *reinterpret_cast<const f16x8*>(&G[e * GS + 128 + lhi * 8]);
            }
            acc = __builtin_amdgcn_mfma_f32_16x16x32_f16(a, b, acc, 0, 0, 0);
            if (lhi == 0) {                          // rows 0..3 = d live in lanes 0..15
#pragma unroll
                for (int rg = 0; rg < 4; ++rg)
                    XSH[rg * 96 + e] = acc[rg] * (1.0f / 138.0f);
            }
        }
    }
    __syncthreads();

    // ---------------- stage 4: res[e][k] = sum_d xs[d][e]*xs[d][k] ----------------
    if (tid < 96) {
        const float xs0 = XSH[tid], xs1 = XSH[96 + tid], xs2 = XSH[192 + tid], xs3 = XSH[288 + tid];
#pragma unroll
        for (int k = 0; k < 8; ++k) {
            float rr = xs0 * XSH[k];
            rr = __builtin_fmaf(xs1, XSH[ 96 + k], rr);
            rr = __builtin_fmaf(xs2, XSH[192 + k], rr);
            rr = __builtin_fmaf(xs3, XSH[288 + k], rr);
            RESH[tid * 8 + k] = rr;
        }
    }
    __syncthreads();

#pragma unroll
    for (int i = 0; i < 3; ++i)
        out[(size_t)n * 768 + i * 256 + tid] = RESH[i * 256 + tid];
}

extern "C" void kernel_launch(void* const* d_in, const int* in_sizes, int n_in,
                              void* d_out, int out_size, void* d_ws, size_t ws_size,
                              hipStream_t stream)
{
    const float* dmat = (const float*)d_in[0];
    const int n_atoms = in_sizes[0] / 552;   // 6144
    f16* ws = (f16*)d_ws;

    setup_weights<<<16, 256, 0, stream>>>(
        (const float*)d_in[3], (const float*)d_in[9],
        (const float*)d_in[5], (const float*)d_in[11], ws);

    emb_main<<<n_atoms, 256, 0, stream>>>(
        dmat,
        (const float*)d_in[1],  (const float*)d_in[2],   // w00, b00
        (const float*)d_in[4],  (const float*)d_in[6],   // b01, b02
        (const float*)d_in[7],  (const float*)d_in[8],   // w10, b10
        (const float*)d_in[10], (const float*)d_in[12],  // b11, b12
        ws, (float*)d_out);
}